// Round 11
// baseline (3441.634 us; speedup 1.0000x reference)
//
#include <hip/hip_runtime.h>

#define NN 20000
#define NE 640000

typedef __attribute__((ext_vector_type(4))) float f4;
typedef __attribute__((ext_vector_type(8))) unsigned short us8;
typedef __attribute__((ext_vector_type(8))) __bf16 bf8;
typedef __attribute__((ext_vector_type(4))) int i4;

__device__ __forceinline__ unsigned short f2bf(float f) {
    union { float f; unsigned int u; } v; v.f = f;
    unsigned int u = v.u;
    return (unsigned short)((u + 0x7FFFu + ((u >> 16) & 1u)) >> 16);
}
__device__ __forceinline__ float bf2f(unsigned short b) {
    union { unsigned int u; float f; } v; v.u = ((unsigned int)b) << 16; return v.f;
}
__device__ __forceinline__ f4 mfma16(us8 a, us8 b, f4 c) {
    return __builtin_amdgcn_mfma_f32_16x16x32_bf16(
        __builtin_bit_cast(bf8, a), __builtin_bit_cast(bf8, b), c, 0, 0, 0);
}
__device__ __forceinline__ void split8(f4 a0, f4 a1, us8& h, us8& l) {
#pragma unroll
    for (int j = 0; j < 4; j++) {
        unsigned short hb = f2bf(a0[j]); h[j] = hb; l[j] = f2bf(a0[j] - bf2f(hb));
        unsigned short hb2 = f2bf(a1[j]); h[4 + j] = hb2; l[4 + j] = f2bf(a1[j] - bf2f(hb2));
    }
}

// ---------------- weight prep ----------------
__global__ void __launch_bounds__(256) prep_weights(
    const float* __restrict__ eW1, const float* __restrict__ eW2,
    const float* __restrict__ nW1, const float* __restrict__ nW2,
    const float* __restrict__ cW1,
    unsigned short* __restrict__ pqW, unsigned short* __restrict__ eW2T,
    unsigned short* __restrict__ nW1T, unsigned short* __restrict__ nW2T,
    unsigned short* __restrict__ cW1T, float* __restrict__ ew1last)
{
    int i = blockIdx.x * 256 + threadIdx.x;
    if (i < 32768) {
        int f = i >> 7, k = i & 127;
        float v = (f < 128) ? eW1[k * 128 + f] : eW1[(128 + k) * 128 + (f - 128)];
        pqW[i] = f2bf(v); return;
    }
    i -= 32768;
    if (i < 16384) { int f = i >> 7, k = i & 127; eW2T[i] = f2bf(eW2[k * 128 + f]); return; }
    i -= 16384;
    if (i < 32768) { int f = i >> 8, k = i & 255; nW1T[i] = f2bf(nW1[k * 128 + f]); return; }
    i -= 32768;
    if (i < 16384) { int f = i >> 7, k = i & 127; nW2T[i] = f2bf(nW2[k * 128 + f]); return; }
    i -= 16384;
    if (i < 16384) { int f = i >> 7, k = i & 127; cW1T[i] = f2bf(cW1[k * 128 + f]); return; }
    i -= 16384;
    if (i < 128) { ew1last[i] = eW1[256 * 128 + i]; }
}

// ---------------- embedding ----------------
__global__ void __launch_bounds__(128) embed_init(
    const float* __restrict__ h_in,
    const float* __restrict__ embW, const float* __restrict__ embB,
    float* __restrict__ h_cur)
{
    int n = blockIdx.x, f = threadIdx.x;
    float acc = embB[f];
#pragma unroll
    for (int p = 0; p < 16; p++) acc += h_in[n * 16 + p] * embW[p * 128 + f];
    h_cur[n * 128 + f] = acc;
}

// ---------------- CSR sort ----------------
__global__ void __launch_bounds__(256) zero_kernel(int* __restrict__ p, int n) {
    int i = blockIdx.x * 256 + threadIdx.x;
    if (i < n) p[i] = 0;
}

__global__ void __launch_bounds__(256) hist_kernel(const int* __restrict__ eidx,
                                                   int* __restrict__ deg) {
    int e = blockIdx.x * 256 + threadIdx.x;
    if (e < NE) atomicAdd(&deg[eidx[e]], 1);
}

__global__ void __launch_bounds__(1024) scan_kernel(const int* __restrict__ deg,
                                                    int* __restrict__ offs) {
    __shared__ int ssum[1024];
    const int t = threadIdx.x;
    const int base = t * 20;
    int loc[20];
    int s = 0;
#pragma unroll
    for (int i = 0; i < 20; i++) {
        int v = (base + i < NN) ? deg[base + i] : 0;
        loc[i] = s; s += v;
    }
    ssum[t] = s;
    __syncthreads();
    for (int d = 1; d < 1024; d <<= 1) {
        int v = (t >= d) ? ssum[t - d] : 0;
        __syncthreads();
        ssum[t] += v;
        __syncthreads();
    }
    int excl = (t == 0) ? 0 : ssum[t - 1];
#pragma unroll
    for (int i = 0; i < 20; i++)
        if (base + i < NN) offs[base + i] = excl + loc[i];
    if (t == 1023) offs[NN] = ssum[1023];
}

__global__ void __launch_bounds__(256) scatter_kernel(
    const int* __restrict__ eidx, const int* __restrict__ offs,
    int* __restrict__ cursor, int* __restrict__ scol)
{
    int e = blockIdx.x * 256 + threadIdx.x;
    if (e >= NE) return;
    int r = eidx[e];
    int pos = offs[r] + atomicAdd(&cursor[r], 1);
    scol[pos] = eidx[NE + e];
}

// ---------------- pq_kernel: P(+eb1) fp32 | Q bf16 = h @ pqW^T --------------
__global__ void __launch_bounds__(256, 2) pq_kernel(
    const float* __restrict__ h_cur, const unsigned short* __restrict__ pqW,
    const float* __restrict__ eb1,
    float* __restrict__ Pb, unsigned short* __restrict__ Qb)
{
    __shared__ __align__(16) char smA[32 * 128 * 4];  // 16KB fp32 h tile
    const int t = threadIdx.x;
    const int n0 = blockIdx.x * 32;

#pragma unroll
    for (int i = 0; i < 4; i++) {
        int c = i * 256 + t;              // 0..1023 f4-chunks
        int nd = c >> 5, q = c & 31;
        f4 v = *reinterpret_cast<const f4*>(h_cur + (size_t)(n0 + nd) * 128 + q * 4);
        int dst = (nd * 512 + q * 16) ^ ((nd & 7) << 5);
        *reinterpret_cast<f4*>(smA + dst) = v;
    }
    __syncthreads();

    const int lane = t & 63, w = t >> 6;
    const int lr = lane & 15, lg = lane >> 4;

    us8 ah[2][4], al[2][4];
#pragma unroll
    for (int rb = 0; rb < 2; rb++) {
        int row = rb * 16 + lr;
#pragma unroll
        for (int ks = 0; ks < 4; ks++) {
            int base = (row * 512 + ks * 128 + lg * 32) ^ ((row & 7) << 5);
            f4 a0 = *reinterpret_cast<const f4*>(smA + base);
            f4 a1 = *reinterpret_cast<const f4*>(smA + base + 16);
            split8(a0, a1, ah[rb][ks], al[rb][ks]);
        }
    }
#pragma unroll
    for (int rb = 0; rb < 2; rb++) {
#pragma unroll
        for (int nt = 0; nt < 4; nt++) {
            int feat = w * 64 + nt * 16 + lr;
            const unsigned short* bp = pqW + feat * 128 + lg * 8;
            f4 a = {0.f, 0.f, 0.f, 0.f};
#pragma unroll
            for (int ks = 0; ks < 4; ks++) {
                us8 b = *reinterpret_cast<const us8*>(bp + ks * 32);
                a = mfma16(ah[rb][ks], b, a);
                a = mfma16(al[rb][ks], b, a);
            }
#pragma unroll
            for (int r = 0; r < 4; r++) {
                int n = n0 + rb * 16 + lg * 4 + r;
                if (feat < 128) Pb[(size_t)n * 128 + feat] = a[r] + eb1[feat];
                else            Qb[(size_t)n * 128 + feat - 128] = f2bf(a[r]);
            }
        }
    }
}

// ---------------- edge kernel: ONE ROW PER WAVE, atomic-free ---------------
// 4 waves/block, wave owns row r = blockIdx*4+w; loops its edges in 16-chunks.
// m accumulated in registers across chunks -> plain stores.
// x_next[r] = x_cur[r] + sum(alpha*rp) -> plain store (x double-buffered).
// LDS: 4KB/wave e_ij bf16 transpose buffer only. No barriers, no atomics.
__global__ void __launch_bounds__(256, 6) edge_kernel(
    const int* __restrict__ scol, const int* __restrict__ offs,
    const float* __restrict__ Pb, const unsigned short* __restrict__ Qb,
    const float* __restrict__ x_cur,
    const unsigned short* __restrict__ eW2T, const unsigned short* __restrict__ cW1T,
    const float* __restrict__ ew1last,
    const float* __restrict__ eb2, const float* __restrict__ cb1,
    const float* __restrict__ cb2, const float* __restrict__ cW2,
    float* __restrict__ m, float* __restrict__ x_next)
{
    __shared__ __align__(16) unsigned short ebuf[4][2048];  // 4KB/wave
    const int t = threadIdx.x;
    const int w = t >> 6, lane = t & 63;
    char* wsm = reinterpret_cast<char*>(ebuf[w]);
    const int r = blockIdx.x * 4 + w;          // 5000 blocks x 4 waves = NN

    const int lr = lane & 15, lg = lane >> 4;
    const int s = offs[r], tend = offs[r + 1];

    const float xr0 = x_cur[r * 3 + 0];
    const float xr1 = x_cur[r * 3 + 1];
    const float xr2 = x_cur[r * 3 + 2];
    const float cb2v = cb2[0];
    const float* pp = Pb + (size_t)r * 128;

    float macc0 = 0.f, macc1 = 0.f;
    float xa0 = 0.f, xa1 = 0.f, xa2 = 0.f;

    for (int cb = s; cb < tend; cb += 16) {
        const int cnt = (tend - cb < 16) ? (tend - cb) : 16;

        // per-edge meta in lanes 0-15 (registers; broadcast via shfl)
        int cval = r; float p0v = 0.f, p1v = 0.f, p2v = 0.f, rdv = 0.f;
        if (lane < cnt) {
            cval = scol[cb + lane];
            p0v = xr0 - x_cur[cval * 3 + 0];
            p1v = xr1 - x_cur[cval * 3 + 1];
            p2v = xr2 - x_cur[cval * 3 + 2];
            rdv = p0v * p0v + p1v * p1v + p2v * p2v;
        }
        const int colE = __shfl(cval, lr);
        const float rd = __shfl(rdv, lr);

        // phase A: z1 = relu(P[r] + Q[col] + rd*wl) directly in A-frag regs
        us8 af[4];
        {
            const unsigned short* qp = Qb + (size_t)colE * 128;
#pragma unroll
            for (int ks = 0; ks < 4; ks++) {
                int f = ks * 32 + lg * 8;
                f4 q0 = *reinterpret_cast<const f4*>(pp + f);
                f4 q1 = *reinterpret_cast<const f4*>(pp + f + 4);
                us8 q  = *reinterpret_cast<const us8*>(qp + f);
                f4 w0 = *reinterpret_cast<const f4*>(ew1last + f);
                f4 w1 = *reinterpret_cast<const f4*>(ew1last + f + 4);
                us8 z;
#pragma unroll
                for (int k = 0; k < 4; k++) {
                    float a = q0[k] + bf2f((unsigned short)q[k])     + rd * w0[k];
                    float b = q1[k] + bf2f((unsigned short)q[4 + k]) + rd * w1[k];
                    a = a > 0.f ? a : 0.f;
                    b = b > 0.f ? b : 0.f;
                    z[k] = f2bf(a); z[4 + k] = f2bf(b);
                }
                af[ks] = z;
            }
        }

        // phase B: GEMM2 e_ij = z1 @ eW2 + eb2 -> bf16 wave LDS
#pragma unroll
        for (int nt = 0; nt < 8; nt++) {
            int feat = nt * 16 + lr;
            const unsigned short* bp = eW2T + feat * 128 + lg * 8;
            f4 a = {0.f, 0.f, 0.f, 0.f};
#pragma unroll
            for (int ks = 0; ks < 4; ks++)
                a = mfma16(af[ks], *reinterpret_cast<const us8*>(bp + ks * 32), a);
            float bias = eb2[feat];
#pragma unroll
            for (int rr = 0; rr < 4; rr++) {
                int e = lg * 4 + rr;
                int ad = (e * 256 + feat * 2) ^ ((e & 7) << 4);
                *reinterpret_cast<unsigned short*>(wsm + ad) = f2bf(a[rr] + bias);
            }
        }

        // phase C: m-accum in registers (feats lane, lane+64); all edges same row
        for (int e = 0; e < cnt; e++) {
            macc0 += bf2f(*reinterpret_cast<const unsigned short*>(
                        wsm + ((e * 256 + lane * 2) ^ ((e & 7) << 4))));
            macc1 += bf2f(*reinterpret_cast<const unsigned short*>(
                        wsm + ((e * 256 + (lane + 64) * 2) ^ ((e & 7) << 4))));
        }

        // phase D: GEMM3 + alpha fused; accumulate x-update in registers
        {
            us8 a3[4];
#pragma unroll
            for (int ks = 0; ks < 4; ks++) {
                int ad = (lr * 256 + (ks * 32 + lg * 8) * 2) ^ ((lr & 7) << 4);
                a3[ks] = *reinterpret_cast<const us8*>(wsm + ad);
            }
            float partial[4] = {0.f, 0.f, 0.f, 0.f};
#pragma unroll
            for (int nt = 0; nt < 8; nt++) {
                int feat = nt * 16 + lr;
                const unsigned short* bp = cW1T + feat * 128 + lg * 8;
                f4 a = {0.f, 0.f, 0.f, 0.f};
#pragma unroll
                for (int ks = 0; ks < 4; ks++)
                    a = mfma16(a3[ks], *reinterpret_cast<const us8*>(bp + ks * 32), a);
                float bias = cb1[feat], wv = cW2[feat];
#pragma unroll
                for (int rr = 0; rr < 4; rr++) {
                    float z = a[rr] + bias;
                    z = z > 0.f ? z : 0.f;
                    partial[rr] += z * wv;
                }
            }
#pragma unroll
            for (int rr = 0; rr < 4; rr++) {
                partial[rr] += __shfl_xor(partial[rr], 1);
                partial[rr] += __shfl_xor(partial[rr], 2);
                partial[rr] += __shfl_xor(partial[rr], 4);
                partial[rr] += __shfl_xor(partial[rr], 8);
            }
#pragma unroll
            for (int rr = 0; rr < 4; rr++) {
                int e = lg * 4 + rr;
                float sq0 = __shfl(p0v, e);
                float sq1 = __shfl(p1v, e);
                float sq2 = __shfl(p2v, e);
                if (e < cnt) {
                    float alpha = partial[rr] + cb2v;
                    xa0 += alpha * sq0;
                    xa1 += alpha * sq1;
                    xa2 += alpha * sq2;
                }
            }
        }
    }

    // plain stores: m (wave owns row r), x_next
    m[(size_t)r * 128 + lane] = macc0;
    m[(size_t)r * 128 + lane + 64] = macc1;

    xa0 += __shfl_xor(xa0, 16); xa0 += __shfl_xor(xa0, 32);
    xa1 += __shfl_xor(xa1, 16); xa1 += __shfl_xor(xa1, 32);
    xa2 += __shfl_xor(xa2, 16); xa2 += __shfl_xor(xa2, 32);
    if (lane == 0) {
        x_next[r * 3 + 0] = xr0 + xa0;
        x_next[r * 3 + 1] = xr1 + xa1;
        x_next[r * 3 + 2] = xr2 + xa2;
    }
}

// ---------------- node update kernel (fp32 A via hi/lo MFMA) ----------------
__global__ void __launch_bounds__(256, 4) node_kernel(
    const unsigned short* __restrict__ nW1T, const unsigned short* __restrict__ nW2T,
    const float* __restrict__ nb1, const float* __restrict__ nb2,
    float* __restrict__ h_cur, const float* __restrict__ m)
{
    __shared__ __align__(16) char smA[32 * 256 * 4];  // [32][256] fp32 [h|m]
    __shared__ unsigned short znb[32 * 128];
    const int t = threadIdx.x;
    const int n0 = blockIdx.x * 32;

#pragma unroll
    for (int i = 0; i < 8; i++) {
        int c = i * 256 + t;
        int nd = c >> 6, q = c & 63;
        const float* src = (q < 32) ? (h_cur + (size_t)(n0 + nd) * 128 + q * 4)
                                    : (m + (size_t)(n0 + nd) * 128 + (q - 32) * 4);
        f4 v = *reinterpret_cast<const f4*>(src);
        int dst = (nd * 1024 + q * 16) ^ ((nd & 7) << 5);
        *reinterpret_cast<f4*>(smA + dst) = v;
    }
    __syncthreads();

    const int lane = t & 63, w = t >> 6;
    const int wm = w & 1, wn = w >> 1;
    const int lr = lane & 15, lg = lane >> 4;
    const int nA = wm * 16 + lr;
    const int nC0 = wm * 16 + lg * 4;

    us8 afh[8], afl[8];
#pragma unroll
    for (int ks = 0; ks < 8; ks++) {
        int base = (nA * 1024 + ks * 128 + lg * 32) ^ ((nA & 7) << 5);
        f4 a0 = *reinterpret_cast<const f4*>(smA + base);
        f4 a1 = *reinterpret_cast<const f4*>(smA + base + 16);
        split8(a0, a1, afh[ks], afl[ks]);
    }
#pragma unroll
    for (int nt = 0; nt < 4; nt++) {
        int feat = wn * 64 + nt * 16 + lr;
        const unsigned short* bp = nW1T + feat * 256 + lg * 8;
        f4 a = {0.f, 0.f, 0.f, 0.f};
#pragma unroll
        for (int ks = 0; ks < 8; ks++) {
            us8 b = *reinterpret_cast<const us8*>(bp + ks * 32);
            a = mfma16(afh[ks], b, a);
            a = mfma16(afl[ks], b, a);
        }
        float bias = nb1[feat];
#pragma unroll
        for (int r = 0; r < 4; r++) {
            float z = a[r] + bias;
            z = z > 0.f ? z : 0.f;
            int nd = nC0 + r;
            int ad = (nd * 256 + feat * 2) ^ ((nd & 7) << 4);
            *reinterpret_cast<unsigned short*>(reinterpret_cast<char*>(znb) + ad) = f2bf(z);
        }
    }
    __syncthreads();

    us8 af2[4];
#pragma unroll
    for (int ks = 0; ks < 4; ks++) {
        int ad = (nA * 256 + ks * 64 + lg * 16) ^ ((nA & 7) << 4);
        af2[ks] = *reinterpret_cast<const us8*>(reinterpret_cast<char*>(znb) + ad);
    }
#pragma unroll
    for (int nt = 0; nt < 4; nt++) {
        int feat = wn * 64 + nt * 16 + lr;
        const unsigned short* bp = nW2T + feat * 128 + lg * 8;
        f4 a = {0.f, 0.f, 0.f, 0.f};
#pragma unroll
        for (int ks = 0; ks < 4; ks++)
            a = mfma16(af2[ks], *reinterpret_cast<const us8*>(bp + ks * 32), a);
        float bias = nb2[feat];
#pragma unroll
        for (int r = 0; r < 4; r++) {
            int nd = nC0 + r;
            int gi = (n0 + nd) * 128 + feat;
            h_cur[gi] = h_cur[gi] + a[r] + bias;
        }
    }
}

__global__ void __launch_bounds__(256) writeout(
    const float* __restrict__ h_cur, const float* __restrict__ x_fin,
    float* __restrict__ out)
{
    int i = blockIdx.x * 256 + threadIdx.x;
    if (i < NN * 128) out[i] = h_cur[i];
    else {
        int j = i - NN * 128;
        if (j < NN * 3) out[i] = x_fin[j];
    }
}

extern "C" void kernel_launch(void* const* d_in, const int* in_sizes, int n_in,
                              void* d_out, int out_size, void* d_ws, size_t ws_size,
                              hipStream_t stream)
{
    (void)in_sizes; (void)n_in; (void)out_size; (void)ws_size;
    const float* h_in = (const float*)d_in[0];
    const float* x_in = (const float*)d_in[1];
    const int* eidx   = (const int*)d_in[2];
    const float* embW = (const float*)d_in[3];
    const float* embB = (const float*)d_in[4];
    const float* eW1  = (const float*)d_in[5];
    const float* eb1  = (const float*)d_in[6];
    const float* eW2  = (const float*)d_in[7];
    const float* eb2  = (const float*)d_in[8];
    const float* nW1  = (const float*)d_in[9];
    const float* nb1  = (const float*)d_in[10];
    const float* nW2  = (const float*)d_in[11];
    const float* nb2  = (const float*)d_in[12];
    const float* cW1  = (const float*)d_in[13];
    const float* cb1  = (const float*)d_in[14];
    const float* cW2  = (const float*)d_in[15];
    const float* cb2  = (const float*)d_in[16];

    char* ws = (char*)d_ws;
    size_t off = 0;
    auto alloc = [&](size_t bytes) -> char* {
        char* p = ws + off;
        off += (bytes + 255) & ~size_t(255);
        return p;
    };
    float* h_cur = (float*)alloc((size_t)NN * 128 * 4);
    float* m     = (float*)alloc((size_t)NN * 128 * 4);
    float* Pb    = (float*)alloc((size_t)NN * 128 * 4);
    unsigned short* Qb = (unsigned short*)alloc((size_t)NN * 128 * 2);
    float* x1    = (float*)alloc((size_t)NN * 3 * 4);
    float* x2    = (float*)alloc((size_t)NN * 3 * 4);
    unsigned short* pqW  = (unsigned short*)alloc(256 * 128 * 2);
    unsigned short* eW2T = (unsigned short*)alloc(128 * 128 * 2);
    unsigned short* nW1T = (unsigned short*)alloc(128 * 256 * 2);
    unsigned short* nW2T = (unsigned short*)alloc(128 * 128 * 2);
    unsigned short* cW1T = (unsigned short*)alloc(128 * 128 * 2);
    float* ew1last = (float*)alloc(128 * 4);
    int* counters = (int*)alloc((size_t)2 * NN * 4);  // deg | cursor
    int* deg    = counters;
    int* cursor = counters + NN;
    int* offs   = (int*)alloc((size_t)(NN + 1) * 4);
    int* scol   = (int*)alloc((size_t)NE * 4);

    zero_kernel<<<(2 * NN + 255) / 256, 256, 0, stream>>>(counters, 2 * NN);
    prep_weights<<<449, 256, 0, stream>>>(eW1, eW2, nW1, nW2, cW1,
                                          pqW, eW2T, nW1T, nW2T, cW1T, ew1last);
    embed_init<<<NN, 128, 0, stream>>>(h_in, embW, embB, h_cur);
    hist_kernel<<<(NE + 255) / 256, 256, 0, stream>>>(eidx, deg);
    scan_kernel<<<1, 1024, 0, stream>>>(deg, offs);
    scatter_kernel<<<(NE + 255) / 256, 256, 0, stream>>>(eidx, offs, cursor, scol);
    pq_kernel<<<NN / 32, 256, 0, stream>>>(h_cur, pqW, eb1, Pb, Qb);

    const float* xr[3] = {x_in, x1, x2};
    float* xw[2] = {x1, x2};
    for (int l = 0; l < 2; l++) {
        edge_kernel<<<NN / 4, 256, 0, stream>>>(scol, offs, Pb, Qb, xr[l],
                                                eW2T, cW1T, ew1last,
                                                eb2, cb1, cb2, cW2, m, xw[l]);
        node_kernel<<<NN / 32, 256, 0, stream>>>(nW1T, nW2T, nb1, nb2, h_cur, m);
        if (l == 0)
            pq_kernel<<<NN / 32, 256, 0, stream>>>(h_cur, pqW, eb1, Pb, Qb);
    }
    writeout<<<(NN * 128 + NN * 3 + 255) / 256, 256, 0, stream>>>(h_cur, x2, (float*)d_out);
}